// Round 13
// baseline (162.297 us; speedup 1.0000x reference)
//
#include <hip/hip_runtime.h>
#include <math.h>

// RechitsGCN fused — round 13: R12 (152.5 µs) + w1/w2 restage.
// w1T->P after B9 (P dead), w2T->W after B10 (wvT dead): deletes the two
// dedicated writeW barrier pairs (16->14 barriers) and shortens w1r/w2r
// register-hold windows to a single phase each.
#define Gg 1024
#define NT 1024

typedef __bf16 bf16x8 __attribute__((ext_vector_type(8)));
typedef float  f32x4  __attribute__((ext_vector_type(4)));

#define P_OFF   0
#define Q_OFF   32768
#define R_OFF   65536
#define W_OFF   98304
#define XB_OFF  131072
#define CO_OFF  141312
#define MS_OFF  142336
#define NK_OFF  142848
#define CS_OFF  143360
#define PL_OFF  145408
#define SN_OFF  149504
#define SMEM_SZ 149520

__device__ __forceinline__ unsigned short f2b(float f){
  return __builtin_bit_cast(unsigned short, (__bf16)f);
}
__device__ __forceinline__ float b2f(unsigned short h){
  return __uint_as_float(((unsigned)h) << 16);
}
__device__ __forceinline__ float frcp(float x){ return __builtin_amdgcn_rcpf(x); }
__device__ __forceinline__ int SW(int row, int bc){ return (row << 8) + (bc ^ ((row & 7) << 4)); }

__device__ __forceinline__ uint4 pk8(const float* f){
  uint4 v;
  v.x = (unsigned)f2b(f[0]) | ((unsigned)f2b(f[1])<<16);
  v.y = (unsigned)f2b(f[2]) | ((unsigned)f2b(f[3])<<16);
  v.z = (unsigned)f2b(f[4]) | ((unsigned)f2b(f[5])<<16);
  v.w = (unsigned)f2b(f[6]) | ((unsigned)f2b(f[7])<<16);
  return v;
}
__device__ __forceinline__ f32x4 MFMA(uint4 a, uint4 b, f32x4 c){
  return __builtin_amdgcn_mfma_f32_16x16x32_bf16(
      __builtin_bit_cast(bf16x8, a), __builtin_bit_cast(bf16x8, b), c, 0, 0, 0);
}
#define ZACC(A) { f32x4 z_={0.f,0.f,0.f,0.f}; A[0]=z_; A[1]=z_; A[2]=z_; A[3]=z_; }

__device__ __forceinline__ void mm_full(f32x4* acc, const char* A, const char* B,
                                        int p, int sub, int l15, int lhi){
  #pragma unroll
  for (int ks = 0; ks < 4; ks++){
    const int kb = ks*64 + lhi*16;
    const uint4 a = *(const uint4*)(A + SW(16*p + l15, kb));
    #pragma unroll
    for (int n0 = 0; n0 < 4; n0++){
      const uint4 b = *(const uint4*)(B + SW((sub*4 + n0)*16 + l15, kb));
      acc[n0] = MFMA(a, b, acc[n0]);
    }
  }
}
__device__ __forceinline__ void mmX(f32x4* acc, const char* Xb, const char* Wt,
                                    int p, int sub, int l15, int lhi){
  const uint4 a = *(const uint4*)(Xb + 80*(16*p + l15) + lhi*16);
  #pragma unroll
  for (int n0 = 0; n0 < 4; n0++){
    const uint4 b = *(const uint4*)(Wt + 80*((sub*4 + n0)*16 + l15) + lhi*16);
    acc[n0] = MFMA(a, b, acc[n0]);
  }
}
__device__ __forceinline__ void frag_store(char* buf, const f32x4* acc,
                                           int p, int sub, int l15, int lhi){
  #pragma unroll
  for (int n0 = 0; n0 < 4; n0++){
    const int col = (sub*4 + n0)*16 + l15;
    #pragma unroll
    for (int q = 0; q < 4; q++)
      *(unsigned short*)(buf + SW(16*p + 4*lhi + q, 2*col)) = f2b(acc[n0][q]);
  }
}
__device__ __forceinline__ void fragT_store(char* buf, const f32x4* acc,
                                            int p, int sub, int l15, int lhi){
  const int row0 = 16*p + 4*lhi;
  #pragma unroll
  for (int n0 = 0; n0 < 4; n0++){
    const int col = (sub*4 + n0)*16 + l15;
    uint2 u;
    u.x = (unsigned)f2b(acc[n0][0]) | ((unsigned)f2b(acc[n0][1])<<16);
    u.y = (unsigned)f2b(acc[n0][2]) | ((unsigned)f2b(acc[n0][3])<<16);
    *(uint2*)(buf + SW(col, 2*row0)) = u;
  }
}
__device__ __forceinline__ void stageW(char* W, const unsigned short* src, int tid){
  #pragma unroll
  for (int q = 0; q < 2; q++){
    const int chunk = q*NT + tid;
    const uint4 v = *(const uint4*)(src + chunk*8);
    *(uint4*)(W + SW(chunk >> 4, (chunk & 15)*16)) = v;
  }
}
__device__ __forceinline__ void loadW(uint4* r, const unsigned short* src, int tid){
  r[0] = *(const uint4*)(src + (size_t)tid*8);
  r[1] = *(const uint4*)(src + (size_t)(NT + tid)*8);
}
__device__ __forceinline__ void writeW(char* W, const uint4* r, int tid){
  *(uint4*)(W + SW(tid >> 4, (tid & 15)*16)) = r[0];
  *(uint4*)(W + SW((NT + tid) >> 4, ((NT + tid) & 15)*16)) = r[1];
}

__global__ __launch_bounds__(128) void prep_wqkT(const float* __restrict__ wq,
                                                 const float* __restrict__ wk,
                                                 unsigned short* __restrict__ ws16){
  __shared__ unsigned short wqb[128*130];
  __shared__ float wkr[128];
  const int h = blockIdx.x, t = threadIdx.x;
  for (int i = t; i < 16384; i += 128){ int a = i >> 7, c = i & 127; wqb[a*130+c] = f2b(wq[i]); }
  wkr[t] = wk[h*128 + t];
  __syncthreads();
  float s = 0.f;
  for (int c = 0; c < 128; c++) s += b2f(wqb[t*130 + c]) * wkr[c];
  ws16[h*128 + t] = f2b(s * 0.08838834764831845f);
}

__global__ __launch_bounds__(256) void prep_T(const float* __restrict__ wv,
                                              const float* __restrict__ w1,
                                              const float* __restrict__ w2,
                                              const float* __restrict__ theta,
                                              const float* __restrict__ w_t,
                                              unsigned short* __restrict__ ws16){
  const int i = blockIdx.x*256 + threadIdx.x;
  if (i < 49152){
    const int which = i >> 14, r = i & 16383;
    const int hh = r >> 7, aa = r & 127;
    const float* s = (which == 0) ? wv : (which == 1) ? w1 : w2;
    ws16[16384 + i] = f2b(s[aa*128 + hh]);
  } else if (i < 57344){
    const int t2 = i - 49152;
    const int mat = t2 >> 12, r = t2 & 4095;
    const int hh = r >> 5, kk = r & 31;
    const float* s = (mat == 0) ? theta : w_t;
    ws16[16384 + i] = (kk < 18) ? f2b(s[kk*128 + hh]) : (unsigned short)0;
  }
}

__global__ void __launch_bounds__(NT)
__attribute__((amdgpu_waves_per_eu(4, 4)))
fused_gcn(const float* __restrict__ x, const float* __restrict__ mask,
          const float* __restrict__ b_t, const unsigned short* __restrict__ ws16,
          const float* __restrict__ b1, const float* __restrict__ b2,
          const float* __restrict__ g_sa, const float* __restrict__ be_sa,
          const float* __restrict__ g_out, const float* __restrict__ be_out,
          float* __restrict__ out)
{
  extern __shared__ char smc[];
  char* Pb = smc + P_OFF;
  char* Qb = smc + Q_OFF;
  char* Rb = smc + R_OFF;
  char* Wb = smc + W_OFF;
  char* Xb = smc + XB_OFF;
  float* coords = (float*)(smc + CO_OFF);
  float* msh    = (float*)(smc + MS_OFF);
  float* nk     = (float*)(smc + NK_OFF);
  float* csum   = (float*)(smc + CS_OFF);
  float* pool   = (float*)(smc + PL_OFF);
  float* sN     = (float*)(smc + SN_OFF);

  const int g    = blockIdx.x;
  const int tid  = threadIdx.x;
  const int lane = tid & 63;
  const int wv_  = tid >> 6;
  const int p    = wv_ >> 1;
  const int sub  = wv_ & 1;
  const int l15  = lane & 15;
  const int lhi  = lane >> 4;
  const int rt2  = tid >> 4;
  const int ct   = tid & 15;

  const size_t gRH = (size_t)g * 16384;
  float* out0  = out;
  float* sa_o  = out + (size_t)Gg*128 + gRH;
  float* den_o = out + (size_t)Gg*128 + (size_t)Gg*16384 + gRH;
  float* att_o = out + (size_t)Gg*128 + 2*(size_t)Gg*16384 + gRH;
  float* adj_o = out + (size_t)Gg*128 + 3*(size_t)Gg*16384 + gRH;

  // ---- S0: stage x->Xb bf16, coords, mask, thetaT/w_tT->W ----
  {
    const float* xg = x + (size_t)g * 2304;
    for (int i = tid; i < 2304; i += NT){
      const int r = (int)(((unsigned)i * 3641u) >> 16);   // i/18 exact for i<2304
      const int k = i - r*18;
      *(unsigned short*)(Xb + r*80 + k*2) = f2b(xg[i]);
    }
    if (tid < 128){
      #pragma unroll
      for (int c = 18; c < 32; c += 2) *(unsigned*)(Xb + tid*80 + c*2) = 0u;
      msh[tid] = mask[(size_t)g*128 + tid];
    }
    if (tid < 256) coords[tid] = xg[(tid >> 1)*18 + (tid & 1)];
    {
      const int which = tid >> 9, t = tid & 511;
      const uint4 v = *(const uint4*)(ws16 + 65536 + which*4096 + t*8);
      *(uint4*)(Wb + which*10240 + (t >> 2)*80 + (t & 3)*16) = v;
    }
  }
  __syncthreads();                                       // B0
  if (tid < 64){                                         // parallel sN (wave 0)
    float v = msh[tid] + msh[tid + 64];
    #pragma unroll
    for (int o = 1; o < 64; o <<= 1) v += __shfl_xor(v, o);
    if (tid == 0) *sN = v;
  }

  // ---- S3 (MFMA): f_het, gate; f_hetT -> Q ----
  f32x4 fhet[4]; float gate[4][4];
  {
    f32x4 gf[4];
    ZACC(fhet); ZACC(gf);
    mmX(fhet, Xb, Wb, p, sub, l15, lhi);
    mmX(gf,   Xb, Wb + 10240, p, sub, l15, lhi);
    #pragma unroll
    for (int n0 = 0; n0 < 4; n0++){
      const float btv = b_t[(sub*4 + n0)*16 + l15];
      #pragma unroll
      for (int q = 0; q < 4; q++)
        gate[n0][q] = frcp(1.f + __expf(-(gf[n0][q] + btv)));
    }
    fragT_store(Qb, fhet, p, sub, l15, lhi);
  }

  // ---- S1: adj exact f32 -> adj_o + regs; deg -> nk ----
  float av[2][8];
  {
    float sc0[8], sc1[8], smv[8];
    #pragma unroll
    for (int j = 0; j < 8; j++){
      const int s = 8*ct + j;
      sc0[j] = coords[2*s]; sc1[j] = coords[2*s + 1]; smv[j] = msh[s];
    }
    #pragma unroll
    for (int i = 0; i < 2; i++){
      const int r = 2*rt2 + i;
      const float c0 = coords[2*r], c1 = coords[2*r + 1];
      const float mr = msh[r];
      float dsum = 0.f;
      #pragma unroll
      for (int j = 0; j < 8; j++){
        const float dx = c0 - sc0[j], dy = c1 - sc1[j];
        float dsq = dx*dx + dy*dy;
        dsq = fmaxf(dsq, 1e-12f);
        const float a = __expf(-__fsqrt_rn(dsq)) * (mr * smv[j]);
        av[i][j] = a; dsum += a;
      }
      #pragma unroll
      for (int o = 1; o < 16; o <<= 1) dsum += __shfl_xor(dsum, o);
      if (ct == 0){ const float t = dsum + 1e-6f; const float rs = __frsqrt_rn(t); nk[r] = rs*rs*rs; }
      *(float4*)(adj_o + (size_t)r*128 + 8*ct)     = make_float4(av[i][0],av[i][1],av[i][2],av[i][3]);
      *(float4*)(adj_o + (size_t)r*128 + 8*ct + 4) = make_float4(av[i][4],av[i][5],av[i][6],av[i][7]);
    }
  }
  __syncthreads();                                       // B1

  // ---- S2: A' = adj^3 * nk[r]*nk[s] -> P ----
  {
    float nkc[8];
    #pragma unroll
    for (int j = 0; j < 8; j++) nkc[j] = nk[8*ct + j];
    #pragma unroll
    for (int i = 0; i < 2; i++){
      const int r = 2*rt2 + i;
      const float nr = nk[r];
      float tv[8];
      #pragma unroll
      for (int j = 0; j < 8; j++){ const float a = av[i][j]; tv[j] = a*a*a*nr*nkc[j]; }
      *(uint4*)(Pb + SW(r, 16*ct)) = pk8(tv);
    }
  }
  __syncthreads();                                       // B2

  stageW(Wb, ws16, tid);                                 // wqkT (overlaps M2)

  // ---- M2: f_hom_pre = A' @ f_het ----
  f32x4 acc[4];
  ZACC(acc);
  mm_full(acc, Pb, Qb, p, sub, l15, lhi);
  __syncthreads();                                       // B4

  // ---- S5: og -> R + ogT -> Q ----
  {
    f32x4 ogv[4];
    #pragma unroll
    for (int n0 = 0; n0 < 4; n0++)
      #pragma unroll
      for (int q = 0; q < 4; q++){
        const float gv = gate[n0][q];
        ogv[n0][q] = gv * fmaxf(acc[n0][q], 0.f) + (1.f - gv) * fhet[n0][q];
      }
    frag_store(Rb, ogv, p, sub, l15, lhi);
    fragT_store(Qb, ogv, p, sub, l15, lhi);
  }
  __syncthreads();                                       // B5

  // ---- M3: t = og @ wqk -> P ----
  ZACC(acc);
  mm_full(acc, Rb, Wb, p, sub, l15, lhi);
  frag_store(Pb, acc, p, sub, l15, lhi);
  __syncthreads();                                       // B6

  stageW(Wb, ws16 + 16384, tid);                         // wvT (overlaps M4)

  // ---- M4: logits; no-max masked softmax ----
  ZACC(acc);
  mm_full(acc, Pb, Rb, p, sub, l15, lhi);
  float ee[4][4];
  {
    float msv[4];
    #pragma unroll
    for (int n0 = 0; n0 < 4; n0++) msv[n0] = msh[(sub*4 + n0)*16 + l15];
    #pragma unroll
    for (int q = 0; q < 4; q++){
      const int row = 16*p + 4*lhi + q;
      float se = 0.f;
      #pragma unroll
      for (int n0 = 0; n0 < 4; n0++){
        const float e = __expf(acc[n0][q]) * msv[n0];
        ee[n0][q] = e; se += e;
      }
      #pragma unroll
      for (int o = 1; o < 16; o <<= 1) se += __shfl_xor(se, o);
      if (l15 == 0) csum[row*2 + sub] = se;
    }
  }
  __syncthreads();                                       // B7
  #pragma unroll
  for (int q = 0; q < 4; q++){
    const int row = 16*p + 4*lhi + q;
    const float inv = frcp(csum[row*2] + csum[row*2 + 1]);
    #pragma unroll
    for (int n0 = 0; n0 < 4; n0++){
      const float a = ee[n0][q] * inv;
      const int col = (sub*4 + n0)*16 + l15;
      att_o[(size_t)row*128 + col] = a;                  // f32
      *(unsigned short*)(Pb + SW(row, 2*col)) = f2b(a);
    }
  }
  __syncthreads();                                       // B8 (attn in P)

  uint4 w1r[2];
  loadW(w1r, ws16 + 32768, tid);                         // w1T -> regs (held M5 only)

  // ---- M5: u = attn @ og -> R ----
  ZACC(acc);
  mm_full(acc, Pb, Qb, p, sub, l15, lhi);
  frag_store(Rb, acc, p, sub, l15, lhi);
  __syncthreads();                                       // B9 (P,Q dead)

  writeW(Pb, w1r, tid);                                  // w1T -> P (overlaps M6)
  uint4 w2r[2];
  loadW(w2r, ws16 + 49152, tid);                         // w2T -> regs (held M6 only)

  // ---- M6: sa_pre = u @ wv ; LN-sum ----
  ZACC(acc);
  mm_full(acc, Rb, Wb, p, sub, l15, lhi);
  {
    #pragma unroll
    for (int q = 0; q < 4; q++){
      const int row = 16*p + 4*lhi + q;
      float s1 = 0.f, s2 = 0.f;
      #pragma unroll
      for (int n0 = 0; n0 < 4; n0++){ const float v = acc[n0][q]; s1 += v; s2 += v*v; }
      #pragma unroll
      for (int o = 1; o < 16; o <<= 1){ s1 += __shfl_xor(s1, o); s2 += __shfl_xor(s2, o); }
      if (l15 == 0){ csum[row*4 + sub*2] = s1; csum[row*4 + sub*2 + 1] = s2; }
    }
  }
  __syncthreads();                                       // B10 (W wvT-reads done)

  writeW(Wb, w2r, tid);                                  // w2T -> W (overlaps LN-apply)

  // ---- LN-apply: sa -> Q + sav regs + global ----
  f32x4 sav[4];
  {
    float gsa[4], bsa[4];
    #pragma unroll
    for (int n0 = 0; n0 < 4; n0++){ const int c = (sub*4+n0)*16 + l15; gsa[n0] = g_sa[c]; bsa[n0] = be_sa[c]; }
    #pragma unroll
    for (int q = 0; q < 4; q++){
      const int row = 16*p + 4*lhi + q;
      const float s1 = csum[row*4] + csum[row*4 + 2];
      const float s2 = csum[row*4 + 1] + csum[row*4 + 3];
      const float mean = s1 * 0.0078125f;
      const float var  = s2 * 0.0078125f - mean*mean;
      const float rstd = __frsqrt_rn(var + 1e-3f);
      const float mr = msh[row];
      #pragma unroll
      for (int n0 = 0; n0 < 4; n0++){
        const float y = ((acc[n0][q] - mean) * rstd * gsa[n0] + bsa[n0]) * mr;
        sav[n0][q] = y;
        sa_o[(size_t)row*128 + (sub*4+n0)*16 + l15] = y;  // f32
      }
    }
    frag_store(Qb, sav, p, sub, l15, lhi);
  }
  __syncthreads();                                       // B11 (sa in Q; w1T in P; w2T in W)

  // ---- M7: d1 = relu(sa @ w1 + b1) -> R (u dead after M6) ----
  ZACC(acc);
  mm_full(acc, Qb, Pb, p, sub, l15, lhi);
  {
    f32x4 d1v[4];
    #pragma unroll
    for (int n0 = 0; n0 < 4; n0++){
      const float b1v = b1[(sub*4 + n0)*16 + l15];
      #pragma unroll
      for (int q = 0; q < 4; q++) d1v[n0][q] = fmaxf(acc[n0][q] + b1v, 0.f);
    }
    frag_store(Rb, d1v, p, sub, l15, lhi);
  }
  __syncthreads();                                       // B12

  // ---- M8: d2=relu(d1@w2+b2); dense=LN(d2+sa)*m -> global; pool ----
  ZACC(acc);
  mm_full(acc, Rb, Wb, p, sub, l15, lhi);
  {
    float b2v[4], gov[4], bov[4], dd[4][4];
    #pragma unroll
    for (int n0 = 0; n0 < 4; n0++){
      const int c = (sub*4 + n0)*16 + l15;
      b2v[n0] = b2[c]; gov[n0] = g_out[c]; bov[n0] = be_out[c];
    }
    #pragma unroll
    for (int q = 0; q < 4; q++){
      const int row = 16*p + 4*lhi + q;
      float s1 = 0.f, s2 = 0.f;
      #pragma unroll
      for (int n0 = 0; n0 < 4; n0++){
        const float v = fmaxf(acc[n0][q] + b2v[n0], 0.f) + sav[n0][q];
        dd[n0][q] = v; s1 += v; s2 += v*v;
      }
      #pragma unroll
      for (int o = 1; o < 16; o <<= 1){ s1 += __shfl_xor(s1, o); s2 += __shfl_xor(s2, o); }
      if (l15 == 0){ csum[row*4 + sub*2] = s1; csum[row*4 + sub*2 + 1] = s2; }
    }
    __syncthreads();                                     // B13
    float cs[4] = {0.f, 0.f, 0.f, 0.f};
    #pragma unroll
    for (int q = 0; q < 4; q++){
      const int row = 16*p + 4*lhi + q;
      const float s1 = csum[row*4] + csum[row*4 + 2];
      const float s2 = csum[row*4 + 1] + csum[row*4 + 3];
      const float mean = s1 * 0.0078125f;
      const float var  = s2 * 0.0078125f - mean*mean;
      const float rstd = __frsqrt_rn(var + 1e-3f);
      const float mr = msh[row];
      #pragma unroll
      for (int n0 = 0; n0 < 4; n0++){
        const float y = ((dd[n0][q] - mean) * rstd * gov[n0] + bov[n0]) * mr;
        den_o[(size_t)row*128 + (sub*4+n0)*16 + l15] = y;  // f32
        cs[n0] += y;
      }
    }
    #pragma unroll
    for (int n0 = 0; n0 < 4; n0++){
      float v = cs[n0];
      v += __shfl_xor(v, 16); v += __shfl_xor(v, 32);
      if (lhi == 0) pool[p*128 + (sub*4 + n0)*16 + l15] = v;
    }
  }
  __syncthreads();                                       // B14 (last)
  if (tid < 128){
    float s = 0.f;
    #pragma unroll
    for (int q = 0; q < 8; q++) s += pool[q*128 + tid];
    const float n = *sN;
    out0[(size_t)g*128 + tid] = (n > 0.f) ? (s * frcp(n)) : 0.f;
  }
}

extern "C" void kernel_launch(void* const* d_in, const int* in_sizes, int n_in,
                              void* d_out, int out_size, void* d_ws, size_t ws_size,
                              hipStream_t stream) {
  (void)in_sizes; (void)n_in; (void)out_size; (void)ws_size;
  const float* x     = (const float*)d_in[0];
  const float* mask  = (const float*)d_in[1];
  const float* theta = (const float*)d_in[2];
  const float* w_t   = (const float*)d_in[3];
  const float* b_t   = (const float*)d_in[4];
  const float* wq    = (const float*)d_in[5];
  const float* wk    = (const float*)d_in[6];
  const float* wvp   = (const float*)d_in[7];
  const float* w1    = (const float*)d_in[8];
  const float* b1    = (const float*)d_in[9];
  const float* w2    = (const float*)d_in[10];
  const float* b2    = (const float*)d_in[11];
  const float* g_sa  = (const float*)d_in[12];
  const float* be_sa = (const float*)d_in[13];
  const float* g_out = (const float*)d_in[14];
  const float* be_out= (const float*)d_in[15];
  unsigned short* ws16 = (unsigned short*)d_ws;

  prep_wqkT<<<dim3(128), dim3(128), 0, stream>>>(wq, wk, ws16);
  prep_T<<<dim3(224), dim3(256), 0, stream>>>(wvp, w1, w2, theta, w_t, ws16);

  (void)hipFuncSetAttribute(reinterpret_cast<const void*>(fused_gcn),
                            hipFuncAttributeMaxDynamicSharedMemorySize, SMEM_SZ);
  fused_gcn<<<dim3(Gg), dim3(NT), SMEM_SZ, stream>>>(
      x, mask, b_t, ws16, b1, b2, g_sa, be_sa, g_out, be_out, (float*)d_out);
}

// Round 14
// 159.467 us; speedup vs baseline: 1.0177x; 1.0177x over previous
//
#include <hip/hip_runtime.h>
#include <math.h>

// RechitsGCN fused — round 14: exact R12 (152.5 µs best) + bias/gain vectors
// (b_t,b1,b2,g_sa,be_sa,g_out,be_out; 3.5 KB) prefetched into spare LDS at S0.
// Removes L2/HBM load latency from the S3/M6/M7/M8 phase critical paths.
// (R13's w1/w2 restage reverted: LDS-write contention regressed it to 162.)
#define Gg 1024
#define NT 1024

typedef __bf16 bf16x8 __attribute__((ext_vector_type(8)));
typedef float  f32x4  __attribute__((ext_vector_type(4)));

#define P_OFF   0
#define Q_OFF   32768
#define R_OFF   65536
#define W_OFF   98304
#define XB_OFF  131072
#define CO_OFF  141312
#define MS_OFF  142336
#define NK_OFF  142848
#define CS_OFF  143360
#define PL_OFF  145408
#define SN_OFF  149504
#define BI_OFF  149520   // 7 x 128 f32: b_t|b1|b2|g_sa|be_sa|g_out|be_out
#define SMEM_SZ 153104

__device__ __forceinline__ unsigned short f2b(float f){
  return __builtin_bit_cast(unsigned short, (__bf16)f);
}
__device__ __forceinline__ float b2f(unsigned short h){
  return __uint_as_float(((unsigned)h) << 16);
}
__device__ __forceinline__ float frcp(float x){ return __builtin_amdgcn_rcpf(x); }
__device__ __forceinline__ int SW(int row, int bc){ return (row << 8) + (bc ^ ((row & 7) << 4)); }

__device__ __forceinline__ uint4 pk8(const float* f){
  uint4 v;
  v.x = (unsigned)f2b(f[0]) | ((unsigned)f2b(f[1])<<16);
  v.y = (unsigned)f2b(f[2]) | ((unsigned)f2b(f[3])<<16);
  v.z = (unsigned)f2b(f[4]) | ((unsigned)f2b(f[5])<<16);
  v.w = (unsigned)f2b(f[6]) | ((unsigned)f2b(f[7])<<16);
  return v;
}
__device__ __forceinline__ f32x4 MFMA(uint4 a, uint4 b, f32x4 c){
  return __builtin_amdgcn_mfma_f32_16x16x32_bf16(
      __builtin_bit_cast(bf16x8, a), __builtin_bit_cast(bf16x8, b), c, 0, 0, 0);
}
#define ZACC(A) { f32x4 z_={0.f,0.f,0.f,0.f}; A[0]=z_; A[1]=z_; A[2]=z_; A[3]=z_; }

__device__ __forceinline__ void mm_full(f32x4* acc, const char* A, const char* B,
                                        int p, int sub, int l15, int lhi){
  #pragma unroll
  for (int ks = 0; ks < 4; ks++){
    const int kb = ks*64 + lhi*16;
    const uint4 a = *(const uint4*)(A + SW(16*p + l15, kb));
    #pragma unroll
    for (int n0 = 0; n0 < 4; n0++){
      const uint4 b = *(const uint4*)(B + SW((sub*4 + n0)*16 + l15, kb));
      acc[n0] = MFMA(a, b, acc[n0]);
    }
  }
}
__device__ __forceinline__ void mmX(f32x4* acc, const char* Xb, const char* Wt,
                                    int p, int sub, int l15, int lhi){
  const uint4 a = *(const uint4*)(Xb + 80*(16*p + l15) + lhi*16);
  #pragma unroll
  for (int n0 = 0; n0 < 4; n0++){
    const uint4 b = *(const uint4*)(Wt + 80*((sub*4 + n0)*16 + l15) + lhi*16);
    acc[n0] = MFMA(a, b, acc[n0]);
  }
}
__device__ __forceinline__ void frag_store(char* buf, const f32x4* acc,
                                           int p, int sub, int l15, int lhi){
  #pragma unroll
  for (int n0 = 0; n0 < 4; n0++){
    const int col = (sub*4 + n0)*16 + l15;
    #pragma unroll
    for (int q = 0; q < 4; q++)
      *(unsigned short*)(buf + SW(16*p + 4*lhi + q, 2*col)) = f2b(acc[n0][q]);
  }
}
__device__ __forceinline__ void fragT_store(char* buf, const f32x4* acc,
                                            int p, int sub, int l15, int lhi){
  const int row0 = 16*p + 4*lhi;
  #pragma unroll
  for (int n0 = 0; n0 < 4; n0++){
    const int col = (sub*4 + n0)*16 + l15;
    uint2 u;
    u.x = (unsigned)f2b(acc[n0][0]) | ((unsigned)f2b(acc[n0][1])<<16);
    u.y = (unsigned)f2b(acc[n0][2]) | ((unsigned)f2b(acc[n0][3])<<16);
    *(uint2*)(buf + SW(col, 2*row0)) = u;
  }
}
__device__ __forceinline__ void stageW(char* W, const unsigned short* src, int tid){
  #pragma unroll
  for (int q = 0; q < 2; q++){
    const int chunk = q*NT + tid;
    const uint4 v = *(const uint4*)(src + chunk*8);
    *(uint4*)(W + SW(chunk >> 4, (chunk & 15)*16)) = v;
  }
}
__device__ __forceinline__ void loadW(uint4* r, const unsigned short* src, int tid){
  r[0] = *(const uint4*)(src + (size_t)tid*8);
  r[1] = *(const uint4*)(src + (size_t)(NT + tid)*8);
}
__device__ __forceinline__ void writeW(char* W, const uint4* r, int tid){
  *(uint4*)(W + SW(tid >> 4, (tid & 15)*16)) = r[0];
  *(uint4*)(W + SW((NT + tid) >> 4, ((NT + tid) & 15)*16)) = r[1];
}

__global__ __launch_bounds__(128) void prep_wqkT(const float* __restrict__ wq,
                                                 const float* __restrict__ wk,
                                                 unsigned short* __restrict__ ws16){
  __shared__ unsigned short wqb[128*130];
  __shared__ float wkr[128];
  const int h = blockIdx.x, t = threadIdx.x;
  for (int i = t; i < 16384; i += 128){ int a = i >> 7, c = i & 127; wqb[a*130+c] = f2b(wq[i]); }
  wkr[t] = wk[h*128 + t];
  __syncthreads();
  float s = 0.f;
  for (int c = 0; c < 128; c++) s += b2f(wqb[t*130 + c]) * wkr[c];
  ws16[h*128 + t] = f2b(s * 0.08838834764831845f);
}

__global__ __launch_bounds__(256) void prep_T(const float* __restrict__ wv,
                                              const float* __restrict__ w1,
                                              const float* __restrict__ w2,
                                              const float* __restrict__ theta,
                                              const float* __restrict__ w_t,
                                              unsigned short* __restrict__ ws16){
  const int i = blockIdx.x*256 + threadIdx.x;
  if (i < 49152){
    const int which = i >> 14, r = i & 16383;
    const int hh = r >> 7, aa = r & 127;
    const float* s = (which == 0) ? wv : (which == 1) ? w1 : w2;
    ws16[16384 + i] = f2b(s[aa*128 + hh]);
  } else if (i < 57344){
    const int t2 = i - 49152;
    const int mat = t2 >> 12, r = t2 & 4095;
    const int hh = r >> 5, kk = r & 31;
    const float* s = (mat == 0) ? theta : w_t;
    ws16[16384 + i] = (kk < 18) ? f2b(s[kk*128 + hh]) : (unsigned short)0;
  }
}

__global__ void __launch_bounds__(NT)
__attribute__((amdgpu_waves_per_eu(4, 4)))
fused_gcn(const float* __restrict__ x, const float* __restrict__ mask,
          const float* __restrict__ b_t, const unsigned short* __restrict__ ws16,
          const float* __restrict__ b1, const float* __restrict__ b2,
          const float* __restrict__ g_sa, const float* __restrict__ be_sa,
          const float* __restrict__ g_out, const float* __restrict__ be_out,
          float* __restrict__ out)
{
  extern __shared__ char smc[];
  char* Pb = smc + P_OFF;
  char* Qb = smc + Q_OFF;
  char* Rb = smc + R_OFF;
  char* Wb = smc + W_OFF;
  char* Xb = smc + XB_OFF;
  float* coords = (float*)(smc + CO_OFF);
  float* msh    = (float*)(smc + MS_OFF);
  float* nk     = (float*)(smc + NK_OFF);
  float* csum   = (float*)(smc + CS_OFF);
  float* pool   = (float*)(smc + PL_OFF);
  float* sN     = (float*)(smc + SN_OFF);
  float* biasv  = (float*)(smc + BI_OFF);   // [0]=b_t [1]=b1 [2]=b2 [3]=g_sa [4]=be_sa [5]=g_out [6]=be_out

  const int g    = blockIdx.x;
  const int tid  = threadIdx.x;
  const int lane = tid & 63;
  const int wv_  = tid >> 6;
  const int p    = wv_ >> 1;
  const int sub  = wv_ & 1;
  const int l15  = lane & 15;
  const int lhi  = lane >> 4;
  const int rt2  = tid >> 4;
  const int ct   = tid & 15;

  const size_t gRH = (size_t)g * 16384;
  float* out0  = out;
  float* sa_o  = out + (size_t)Gg*128 + gRH;
  float* den_o = out + (size_t)Gg*128 + (size_t)Gg*16384 + gRH;
  float* att_o = out + (size_t)Gg*128 + 2*(size_t)Gg*16384 + gRH;
  float* adj_o = out + (size_t)Gg*128 + 3*(size_t)Gg*16384 + gRH;

  // ---- S0: stage x->Xb bf16, coords, mask, thetaT/w_tT->W, bias vectors->LDS ----
  {
    const float* xg = x + (size_t)g * 2304;
    for (int i = tid; i < 2304; i += NT){
      const int r = (int)(((unsigned)i * 3641u) >> 16);   // i/18 exact for i<2304
      const int k = i - r*18;
      *(unsigned short*)(Xb + r*80 + k*2) = f2b(xg[i]);
    }
    if (tid < 128){
      #pragma unroll
      for (int c = 18; c < 32; c += 2) *(unsigned*)(Xb + tid*80 + c*2) = 0u;
      msh[tid] = mask[(size_t)g*128 + tid];
    }
    if (tid < 256) coords[tid] = xg[(tid >> 1)*18 + (tid & 1)];
    {
      const int which = tid >> 9, t = tid & 511;
      const uint4 v = *(const uint4*)(ws16 + 65536 + which*4096 + t*8);
      *(uint4*)(Wb + which*10240 + (t >> 2)*80 + (t & 3)*16) = v;
    }
    if (tid < 896){
      const int w = tid >> 7, ix = tid & 127;
      const float* sp = (w == 0) ? b_t : (w == 1) ? b1 : (w == 2) ? b2 :
                        (w == 3) ? g_sa : (w == 4) ? be_sa : (w == 5) ? g_out : be_out;
      biasv[tid] = sp[ix];
    }
  }
  __syncthreads();                                       // B0
  if (tid < 64){                                         // parallel sN (wave 0)
    float v = msh[tid] + msh[tid + 64];
    #pragma unroll
    for (int o = 1; o < 64; o <<= 1) v += __shfl_xor(v, o);
    if (tid == 0) *sN = v;
  }

  // ---- S3 (MFMA): f_het, gate; f_hetT -> Q ----
  f32x4 fhet[4]; float gate[4][4];
  {
    f32x4 gf[4];
    ZACC(fhet); ZACC(gf);
    mmX(fhet, Xb, Wb, p, sub, l15, lhi);
    mmX(gf,   Xb, Wb + 10240, p, sub, l15, lhi);
    #pragma unroll
    for (int n0 = 0; n0 < 4; n0++){
      const float btv = biasv[(sub*4 + n0)*16 + l15];
      #pragma unroll
      for (int q = 0; q < 4; q++)
        gate[n0][q] = frcp(1.f + __expf(-(gf[n0][q] + btv)));
    }
    fragT_store(Qb, fhet, p, sub, l15, lhi);
  }

  // ---- S1: adj exact f32 -> adj_o + regs; deg -> nk ----
  float av[2][8];
  {
    float sc0[8], sc1[8], smv[8];
    #pragma unroll
    for (int j = 0; j < 8; j++){
      const int s = 8*ct + j;
      sc0[j] = coords[2*s]; sc1[j] = coords[2*s + 1]; smv[j] = msh[s];
    }
    #pragma unroll
    for (int i = 0; i < 2; i++){
      const int r = 2*rt2 + i;
      const float c0 = coords[2*r], c1 = coords[2*r + 1];
      const float mr = msh[r];
      float dsum = 0.f;
      #pragma unroll
      for (int j = 0; j < 8; j++){
        const float dx = c0 - sc0[j], dy = c1 - sc1[j];
        float dsq = dx*dx + dy*dy;
        dsq = fmaxf(dsq, 1e-12f);
        const float a = __expf(-__fsqrt_rn(dsq)) * (mr * smv[j]);
        av[i][j] = a; dsum += a;
      }
      #pragma unroll
      for (int o = 1; o < 16; o <<= 1) dsum += __shfl_xor(dsum, o);
      if (ct == 0){ const float t = dsum + 1e-6f; const float rs = __frsqrt_rn(t); nk[r] = rs*rs*rs; }
      *(float4*)(adj_o + (size_t)r*128 + 8*ct)     = make_float4(av[i][0],av[i][1],av[i][2],av[i][3]);
      *(float4*)(adj_o + (size_t)r*128 + 8*ct + 4) = make_float4(av[i][4],av[i][5],av[i][6],av[i][7]);
    }
  }
  __syncthreads();                                       // B1

  // ---- S2: A' = adj^3 * nk[r]*nk[s] -> P ----
  {
    float nkc[8];
    #pragma unroll
    for (int j = 0; j < 8; j++) nkc[j] = nk[8*ct + j];
    #pragma unroll
    for (int i = 0; i < 2; i++){
      const int r = 2*rt2 + i;
      const float nr = nk[r];
      float tv[8];
      #pragma unroll
      for (int j = 0; j < 8; j++){ const float a = av[i][j]; tv[j] = a*a*a*nr*nkc[j]; }
      *(uint4*)(Pb + SW(r, 16*ct)) = pk8(tv);
    }
  }
  __syncthreads();                                       // B2

  stageW(Wb, ws16, tid);                                 // wqkT (overlaps M2)

  // ---- M2: f_hom_pre = A' @ f_het ----
  f32x4 acc[4];
  ZACC(acc);
  mm_full(acc, Pb, Qb, p, sub, l15, lhi);
  __syncthreads();                                       // B4

  // ---- S5: og -> R + ogT -> Q ----
  {
    f32x4 ogv[4];
    #pragma unroll
    for (int n0 = 0; n0 < 4; n0++)
      #pragma unroll
      for (int q = 0; q < 4; q++){
        const float gv = gate[n0][q];
        ogv[n0][q] = gv * fmaxf(acc[n0][q], 0.f) + (1.f - gv) * fhet[n0][q];
      }
    frag_store(Rb, ogv, p, sub, l15, lhi);
    fragT_store(Qb, ogv, p, sub, l15, lhi);
  }
  __syncthreads();                                       // B5

  // ---- M3: t = og @ wqk -> P ----
  ZACC(acc);
  mm_full(acc, Rb, Wb, p, sub, l15, lhi);
  frag_store(Pb, acc, p, sub, l15, lhi);
  __syncthreads();                                       // B6

  stageW(Wb, ws16 + 16384, tid);                         // wvT (overlaps M4/M5)

  // ---- M4: logits; no-max masked softmax ----
  ZACC(acc);
  mm_full(acc, Pb, Rb, p, sub, l15, lhi);
  float ee[4][4];
  {
    float msv[4];
    #pragma unroll
    for (int n0 = 0; n0 < 4; n0++) msv[n0] = msh[(sub*4 + n0)*16 + l15];
    #pragma unroll
    for (int q = 0; q < 4; q++){
      const int row = 16*p + 4*lhi + q;
      float se = 0.f;
      #pragma unroll
      for (int n0 = 0; n0 < 4; n0++){
        const float e = __expf(acc[n0][q]) * msv[n0];
        ee[n0][q] = e; se += e;
      }
      #pragma unroll
      for (int o = 1; o < 16; o <<= 1) se += __shfl_xor(se, o);
      if (l15 == 0) csum[row*2 + sub] = se;
    }
  }
  __syncthreads();                                       // B7
  #pragma unroll
  for (int q = 0; q < 4; q++){
    const int row = 16*p + 4*lhi + q;
    const float inv = frcp(csum[row*2] + csum[row*2 + 1]);
    #pragma unroll
    for (int n0 = 0; n0 < 4; n0++){
      const float a = ee[n0][q] * inv;
      const int col = (sub*4 + n0)*16 + l15;
      att_o[(size_t)row*128 + col] = a;                  // f32
      *(unsigned short*)(Pb + SW(row, 2*col)) = f2b(a);
    }
  }
  __syncthreads();                                       // B8

  uint4 w1r[2];
  loadW(w1r, ws16 + 32768, tid);                         // w1T -> regs (in flight)

  // ---- M5: u = attn @ og -> R ----
  ZACC(acc);
  mm_full(acc, Pb, Qb, p, sub, l15, lhi);
  frag_store(Rb, acc, p, sub, l15, lhi);
  __syncthreads();                                       // B9

  // ---- M6: sa = LN(u @ wv)*m -> Q + global + regs ----
  ZACC(acc);
  mm_full(acc, Rb, Wb, p, sub, l15, lhi);
  f32x4 sav[4];
  {
    #pragma unroll
    for (int q = 0; q < 4; q++){
      const int row = 16*p + 4*lhi + q;
      float s1 = 0.f, s2 = 0.f;
      #pragma unroll
      for (int n0 = 0; n0 < 4; n0++){ const float v = acc[n0][q]; s1 += v; s2 += v*v; }
      #pragma unroll
      for (int o = 1; o < 16; o <<= 1){ s1 += __shfl_xor(s1, o); s2 += __shfl_xor(s2, o); }
      if (l15 == 0){ csum[row*4 + sub*2] = s1; csum[row*4 + sub*2 + 1] = s2; }
    }
  }
  __syncthreads();                                       // B10
  {
    float gsa[4], bsa[4];
    #pragma unroll
    for (int n0 = 0; n0 < 4; n0++){
      const int c = (sub*4+n0)*16 + l15;
      gsa[n0] = biasv[384 + c]; bsa[n0] = biasv[512 + c];
    }
    #pragma unroll
    for (int q = 0; q < 4; q++){
      const int row = 16*p + 4*lhi + q;
      const float s1 = csum[row*4] + csum[row*4 + 2];
      const float s2 = csum[row*4 + 1] + csum[row*4 + 3];
      const float mean = s1 * 0.0078125f;
      const float var  = s2 * 0.0078125f - mean*mean;
      const float rstd = __frsqrt_rn(var + 1e-3f);
      const float mr = msh[row];
      #pragma unroll
      for (int n0 = 0; n0 < 4; n0++){
        const float y = ((acc[n0][q] - mean) * rstd * gsa[n0] + bsa[n0]) * mr;
        sav[n0][q] = y;
        sa_o[(size_t)row*128 + (sub*4+n0)*16 + l15] = y;  // f32
      }
    }
    frag_store(Qb, sav, p, sub, l15, lhi);
  }
  __syncthreads();                                       // B11
  writeW(Wb, w1r, tid);                                  // w1T -> LDS
  __syncthreads();                                       // B12

  // ---- M7: d1 = relu(sa @ w1 + b1) -> P ----
  ZACC(acc);
  mm_full(acc, Qb, Wb, p, sub, l15, lhi);
  {
    f32x4 d1v[4];
    #pragma unroll
    for (int n0 = 0; n0 < 4; n0++){
      const float b1v = biasv[128 + (sub*4 + n0)*16 + l15];
      #pragma unroll
      for (int q = 0; q < 4; q++) d1v[n0][q] = fmaxf(acc[n0][q] + b1v, 0.f);
    }
    frag_store(Pb, d1v, p, sub, l15, lhi);
  }
  uint4 w2r[2];
  loadW(w2r, ws16 + 49152, tid);                         // w2T -> regs
  __syncthreads();                                       // B13
  writeW(Wb, w2r, tid);
  __syncthreads();                                       // B14

  // ---- M8: d2=relu(d1@w2+b2); dense=LN(d2+sa)*m -> global; pool ----
  ZACC(acc);
  mm_full(acc, Pb, Wb, p, sub, l15, lhi);
  {
    float b2v[4], gov[4], bov[4], dd[4][4];
    #pragma unroll
    for (int n0 = 0; n0 < 4; n0++){
      const int c = (sub*4 + n0)*16 + l15;
      b2v[n0] = biasv[256 + c]; gov[n0] = biasv[640 + c]; bov[n0] = biasv[768 + c];
    }
    #pragma unroll
    for (int q = 0; q < 4; q++){
      const int row = 16*p + 4*lhi + q;
      float s1 = 0.f, s2 = 0.f;
      #pragma unroll
      for (int n0 = 0; n0 < 4; n0++){
        const float v = fmaxf(acc[n0][q] + b2v[n0], 0.f) + sav[n0][q];
        dd[n0][q] = v; s1 += v; s2 += v*v;
      }
      #pragma unroll
      for (int o = 1; o < 16; o <<= 1){ s1 += __shfl_xor(s1, o); s2 += __shfl_xor(s2, o); }
      if (l15 == 0){ csum[row*4 + sub*2] = s1; csum[row*4 + sub*2 + 1] = s2; }
    }
    __syncthreads();                                     // B15
    float cs[4] = {0.f, 0.f, 0.f, 0.f};
    #pragma unroll
    for (int q = 0; q < 4; q++){
      const int row = 16*p + 4*lhi + q;
      const float s1 = csum[row*4] + csum[row*4 + 2];
      const float s2 = csum[row*4 + 1] + csum[row*4 + 3];
      const float mean = s1 * 0.0078125f;
      const float var  = s2 * 0.0078125f - mean*mean;
      const float rstd = __frsqrt_rn(var + 1e-3f);
      const float mr = msh[row];
      #pragma unroll
      for (int n0 = 0; n0 < 4; n0++){
        const float y = ((dd[n0][q] - mean) * rstd * gov[n0] + bov[n0]) * mr;
        den_o[(size_t)row*128 + (sub*4+n0)*16 + l15] = y;  // f32
        cs[n0] += y;
      }
    }
    #pragma unroll
    for (int n0 = 0; n0 < 4; n0++){
      float v = cs[n0];
      v += __shfl_xor(v, 16); v += __shfl_xor(v, 32);
      if (lhi == 0) pool[p*128 + (sub*4 + n0)*16 + l15] = v;
    }
  }
  __syncthreads();                                       // B16
  if (tid < 128){
    float s = 0.f;
    #pragma unroll
    for (int q = 0; q < 8; q++) s += pool[q*128 + tid];
    const float n = *sN;
    out0[(size_t)g*128 + tid] = (n > 0.f) ? (s * frcp(n)) : 0.f;
  }
}

extern "C" void kernel_launch(void* const* d_in, const int* in_sizes, int n_in,
                              void* d_out, int out_size, void* d_ws, size_t ws_size,
                              hipStream_t stream) {
  (void)in_sizes; (void)n_in; (void)out_size; (void)ws_size;
  const float* x     = (const float*)d_in[0];
  const float* mask  = (const float*)d_in[1];
  const float* theta = (const float*)d_in[2];
  const float* w_t   = (const float*)d_in[3];
  const float* b_t   = (const float*)d_in[4];
  const float* wq    = (const float*)d_in[5];
  const float* wk    = (const float*)d_in[6];
  const float* wvp   = (const float*)d_in[7];
  const float* w1    = (const float*)d_in[8];
  const float* b1    = (const float*)d_in[9];
  const float* w2    = (const float*)d_in[10];
  const float* b2    = (const float*)d_in[11];
  const float* g_sa  = (const float*)d_in[12];
  const float* be_sa = (const float*)d_in[13];
  const float* g_out = (const float*)d_in[14];
  const float* be_out= (const float*)d_in[15];
  unsigned short* ws16 = (unsigned short*)d_ws;

  prep_wqkT<<<dim3(128), dim3(128), 0, stream>>>(wq, wk, ws16);
  prep_T<<<dim3(224), dim3(256), 0, stream>>>(wvp, w1, w2, theta, w_t, ws16);

  (void)hipFuncSetAttribute(reinterpret_cast<const void*>(fused_gcn),
                            hipFuncAttributeMaxDynamicSharedMemorySize, SMEM_SZ);
  fused_gcn<<<dim3(Gg), dim3(NT), SMEM_SZ, stream>>>(
      x, mask, b_t, ws16, b1, b2, g_sa, be_sa, g_out, be_out, (float*)d_out);
}

// Round 15
// 152.769 us; speedup vs baseline: 1.0624x; 1.0438x over previous
//
#include <hip/hip_runtime.h>
#include <math.h>

// RechitsGCN fused — round 15: exact restore of round 12 (152.5 µs, session
// best). R13 (w1/w2 restage, 162) and R14 (bias prefetch, 159.5) both
// regressed and are reverted. Final form: one WG (16 waves) per (b,c) group,
// all six 128^3 matmuls on MFMA via swizzled bf16 LDS tiles, fast-math VALU
// chain, 17-barrier serial schedule (every motion of it tested and worse).
#define Gg 1024
#define NT 1024

typedef __bf16 bf16x8 __attribute__((ext_vector_type(8)));
typedef float  f32x4  __attribute__((ext_vector_type(4)));

#define P_OFF   0
#define Q_OFF   32768
#define R_OFF   65536
#define W_OFF   98304
#define XB_OFF  131072
#define CO_OFF  141312
#define MS_OFF  142336
#define NK_OFF  142848
#define CS_OFF  143360
#define PL_OFF  145408
#define SN_OFF  149504
#define SMEM_SZ 149520

__device__ __forceinline__ unsigned short f2b(float f){
  return __builtin_bit_cast(unsigned short, (__bf16)f);
}
__device__ __forceinline__ float b2f(unsigned short h){
  return __uint_as_float(((unsigned)h) << 16);
}
__device__ __forceinline__ float frcp(float x){ return __builtin_amdgcn_rcpf(x); }
__device__ __forceinline__ int SW(int row, int bc){ return (row << 8) + (bc ^ ((row & 7) << 4)); }

__device__ __forceinline__ uint4 pk8(const float* f){
  uint4 v;
  v.x = (unsigned)f2b(f[0]) | ((unsigned)f2b(f[1])<<16);
  v.y = (unsigned)f2b(f[2]) | ((unsigned)f2b(f[3])<<16);
  v.z = (unsigned)f2b(f[4]) | ((unsigned)f2b(f[5])<<16);
  v.w = (unsigned)f2b(f[6]) | ((unsigned)f2b(f[7])<<16);
  return v;
}
__device__ __forceinline__ f32x4 MFMA(uint4 a, uint4 b, f32x4 c){
  return __builtin_amdgcn_mfma_f32_16x16x32_bf16(
      __builtin_bit_cast(bf16x8, a), __builtin_bit_cast(bf16x8, b), c, 0, 0, 0);
}
#define ZACC(A) { f32x4 z_={0.f,0.f,0.f,0.f}; A[0]=z_; A[1]=z_; A[2]=z_; A[3]=z_; }

__device__ __forceinline__ void mm_full(f32x4* acc, const char* A, const char* B,
                                        int p, int sub, int l15, int lhi){
  #pragma unroll
  for (int ks = 0; ks < 4; ks++){
    const int kb = ks*64 + lhi*16;
    const uint4 a = *(const uint4*)(A + SW(16*p + l15, kb));
    #pragma unroll
    for (int n0 = 0; n0 < 4; n0++){
      const uint4 b = *(const uint4*)(B + SW((sub*4 + n0)*16 + l15, kb));
      acc[n0] = MFMA(a, b, acc[n0]);
    }
  }
}
__device__ __forceinline__ void mmX(f32x4* acc, const char* Xb, const char* Wt,
                                    int p, int sub, int l15, int lhi){
  const uint4 a = *(const uint4*)(Xb + 80*(16*p + l15) + lhi*16);
  #pragma unroll
  for (int n0 = 0; n0 < 4; n0++){
    const uint4 b = *(const uint4*)(Wt + 80*((sub*4 + n0)*16 + l15) + lhi*16);
    acc[n0] = MFMA(a, b, acc[n0]);
  }
}
__device__ __forceinline__ void frag_store(char* buf, const f32x4* acc,
                                           int p, int sub, int l15, int lhi){
  #pragma unroll
  for (int n0 = 0; n0 < 4; n0++){
    const int col = (sub*4 + n0)*16 + l15;
    #pragma unroll
    for (int q = 0; q < 4; q++)
      *(unsigned short*)(buf + SW(16*p + 4*lhi + q, 2*col)) = f2b(acc[n0][q]);
  }
}
__device__ __forceinline__ void fragT_store(char* buf, const f32x4* acc,
                                            int p, int sub, int l15, int lhi){
  const int row0 = 16*p + 4*lhi;
  #pragma unroll
  for (int n0 = 0; n0 < 4; n0++){
    const int col = (sub*4 + n0)*16 + l15;
    uint2 u;
    u.x = (unsigned)f2b(acc[n0][0]) | ((unsigned)f2b(acc[n0][1])<<16);
    u.y = (unsigned)f2b(acc[n0][2]) | ((unsigned)f2b(acc[n0][3])<<16);
    *(uint2*)(buf + SW(col, 2*row0)) = u;
  }
}
__device__ __forceinline__ void stageW(char* W, const unsigned short* src, int tid){
  #pragma unroll
  for (int q = 0; q < 2; q++){
    const int chunk = q*NT + tid;
    const uint4 v = *(const uint4*)(src + chunk*8);
    *(uint4*)(W + SW(chunk >> 4, (chunk & 15)*16)) = v;
  }
}
__device__ __forceinline__ void loadW(uint4* r, const unsigned short* src, int tid){
  r[0] = *(const uint4*)(src + (size_t)tid*8);
  r[1] = *(const uint4*)(src + (size_t)(NT + tid)*8);
}
__device__ __forceinline__ void writeW(char* W, const uint4* r, int tid){
  *(uint4*)(W + SW(tid >> 4, (tid & 15)*16)) = r[0];
  *(uint4*)(W + SW((NT + tid) >> 4, ((NT + tid) & 15)*16)) = r[1];
}

__global__ __launch_bounds__(128) void prep_wqkT(const float* __restrict__ wq,
                                                 const float* __restrict__ wk,
                                                 unsigned short* __restrict__ ws16){
  __shared__ unsigned short wqb[128*130];
  __shared__ float wkr[128];
  const int h = blockIdx.x, t = threadIdx.x;
  for (int i = t; i < 16384; i += 128){ int a = i >> 7, c = i & 127; wqb[a*130+c] = f2b(wq[i]); }
  wkr[t] = wk[h*128 + t];
  __syncthreads();
  float s = 0.f;
  for (int c = 0; c < 128; c++) s += b2f(wqb[t*130 + c]) * wkr[c];
  ws16[h*128 + t] = f2b(s * 0.08838834764831845f);
}

__global__ __launch_bounds__(256) void prep_T(const float* __restrict__ wv,
                                              const float* __restrict__ w1,
                                              const float* __restrict__ w2,
                                              const float* __restrict__ theta,
                                              const float* __restrict__ w_t,
                                              unsigned short* __restrict__ ws16){
  const int i = blockIdx.x*256 + threadIdx.x;
  if (i < 49152){
    const int which = i >> 14, r = i & 16383;
    const int hh = r >> 7, aa = r & 127;
    const float* s = (which == 0) ? wv : (which == 1) ? w1 : w2;
    ws16[16384 + i] = f2b(s[aa*128 + hh]);
  } else if (i < 57344){
    const int t2 = i - 49152;
    const int mat = t2 >> 12, r = t2 & 4095;
    const int hh = r >> 5, kk = r & 31;
    const float* s = (mat == 0) ? theta : w_t;
    ws16[16384 + i] = (kk < 18) ? f2b(s[kk*128 + hh]) : (unsigned short)0;
  }
}

__global__ void __launch_bounds__(NT)
__attribute__((amdgpu_waves_per_eu(4, 4)))
fused_gcn(const float* __restrict__ x, const float* __restrict__ mask,
          const float* __restrict__ b_t, const unsigned short* __restrict__ ws16,
          const float* __restrict__ b1, const float* __restrict__ b2,
          const float* __restrict__ g_sa, const float* __restrict__ be_sa,
          const float* __restrict__ g_out, const float* __restrict__ be_out,
          float* __restrict__ out)
{
  extern __shared__ char smc[];
  char* Pb = smc + P_OFF;
  char* Qb = smc + Q_OFF;
  char* Rb = smc + R_OFF;
  char* Wb = smc + W_OFF;
  char* Xb = smc + XB_OFF;
  float* coords = (float*)(smc + CO_OFF);
  float* msh    = (float*)(smc + MS_OFF);
  float* nk     = (float*)(smc + NK_OFF);
  float* csum   = (float*)(smc + CS_OFF);
  float* pool   = (float*)(smc + PL_OFF);
  float* sN     = (float*)(smc + SN_OFF);

  const int g    = blockIdx.x;
  const int tid  = threadIdx.x;
  const int lane = tid & 63;
  const int wv_  = tid >> 6;
  const int p    = wv_ >> 1;
  const int sub  = wv_ & 1;
  const int l15  = lane & 15;
  const int lhi  = lane >> 4;
  const int rt2  = tid >> 4;
  const int ct   = tid & 15;

  const size_t gRH = (size_t)g * 16384;
  float* out0  = out;
  float* sa_o  = out + (size_t)Gg*128 + gRH;
  float* den_o = out + (size_t)Gg*128 + (size_t)Gg*16384 + gRH;
  float* att_o = out + (size_t)Gg*128 + 2*(size_t)Gg*16384 + gRH;
  float* adj_o = out + (size_t)Gg*128 + 3*(size_t)Gg*16384 + gRH;

  // ---- S0: stage x->Xb bf16, coords, mask, thetaT/w_tT->W ----
  {
    const float* xg = x + (size_t)g * 2304;
    for (int i = tid; i < 2304; i += NT){
      const int r = (int)(((unsigned)i * 3641u) >> 16);   // i/18 exact for i<2304
      const int k = i - r*18;
      *(unsigned short*)(Xb + r*80 + k*2) = f2b(xg[i]);
    }
    if (tid < 128){
      #pragma unroll
      for (int c = 18; c < 32; c += 2) *(unsigned*)(Xb + tid*80 + c*2) = 0u;
      msh[tid] = mask[(size_t)g*128 + tid];
    }
    if (tid < 256) coords[tid] = xg[(tid >> 1)*18 + (tid & 1)];
    {
      const int which = tid >> 9, t = tid & 511;
      const uint4 v = *(const uint4*)(ws16 + 65536 + which*4096 + t*8);
      *(uint4*)(Wb + which*10240 + (t >> 2)*80 + (t & 3)*16) = v;
    }
  }
  __syncthreads();                                       // B0
  if (tid < 64){                                         // parallel sN (wave 0)
    float v = msh[tid] + msh[tid + 64];
    #pragma unroll
    for (int o = 1; o < 64; o <<= 1) v += __shfl_xor(v, o);
    if (tid == 0) *sN = v;
  }

  // ---- S3 (MFMA): f_het, gate; f_hetT -> Q ----
  f32x4 fhet[4]; float gate[4][4];
  {
    f32x4 gf[4];
    ZACC(fhet); ZACC(gf);
    mmX(fhet, Xb, Wb, p, sub, l15, lhi);
    mmX(gf,   Xb, Wb + 10240, p, sub, l15, lhi);
    #pragma unroll
    for (int n0 = 0; n0 < 4; n0++){
      const float btv = b_t[(sub*4 + n0)*16 + l15];
      #pragma unroll
      for (int q = 0; q < 4; q++)
        gate[n0][q] = frcp(1.f + __expf(-(gf[n0][q] + btv)));
    }
    fragT_store(Qb, fhet, p, sub, l15, lhi);
  }

  // ---- S1: adj exact f32 -> adj_o + regs; deg -> nk ----
  float av[2][8];
  {
    float sc0[8], sc1[8], smv[8];
    #pragma unroll
    for (int j = 0; j < 8; j++){
      const int s = 8*ct + j;
      sc0[j] = coords[2*s]; sc1[j] = coords[2*s + 1]; smv[j] = msh[s];
    }
    #pragma unroll
    for (int i = 0; i < 2; i++){
      const int r = 2*rt2 + i;
      const float c0 = coords[2*r], c1 = coords[2*r + 1];
      const float mr = msh[r];
      float dsum = 0.f;
      #pragma unroll
      for (int j = 0; j < 8; j++){
        const float dx = c0 - sc0[j], dy = c1 - sc1[j];
        float dsq = dx*dx + dy*dy;
        dsq = fmaxf(dsq, 1e-12f);
        const float a = __expf(-__fsqrt_rn(dsq)) * (mr * smv[j]);
        av[i][j] = a; dsum += a;
      }
      #pragma unroll
      for (int o = 1; o < 16; o <<= 1) dsum += __shfl_xor(dsum, o);
      if (ct == 0){ const float t = dsum + 1e-6f; const float rs = __frsqrt_rn(t); nk[r] = rs*rs*rs; }
      *(float4*)(adj_o + (size_t)r*128 + 8*ct)     = make_float4(av[i][0],av[i][1],av[i][2],av[i][3]);
      *(float4*)(adj_o + (size_t)r*128 + 8*ct + 4) = make_float4(av[i][4],av[i][5],av[i][6],av[i][7]);
    }
  }
  __syncthreads();                                       // B1

  // ---- S2: A' = adj^3 * nk[r]*nk[s] -> P ----
  {
    float nkc[8];
    #pragma unroll
    for (int j = 0; j < 8; j++) nkc[j] = nk[8*ct + j];
    #pragma unroll
    for (int i = 0; i < 2; i++){
      const int r = 2*rt2 + i;
      const float nr = nk[r];
      float tv[8];
      #pragma unroll
      for (int j = 0; j < 8; j++){ const float a = av[i][j]; tv[j] = a*a*a*nr*nkc[j]; }
      *(uint4*)(Pb + SW(r, 16*ct)) = pk8(tv);
    }
  }
  __syncthreads();                                       // B2

  stageW(Wb, ws16, tid);                                 // wqkT (overlaps M2)

  // ---- M2: f_hom_pre = A' @ f_het ----
  f32x4 acc[4];
  ZACC(acc);
  mm_full(acc, Pb, Qb, p, sub, l15, lhi);
  __syncthreads();                                       // B4

  // ---- S5: og -> R + ogT -> Q ----
  {
    f32x4 ogv[4];
    #pragma unroll
    for (int n0 = 0; n0 < 4; n0++)
      #pragma unroll
      for (int q = 0; q < 4; q++){
        const float gv = gate[n0][q];
        ogv[n0][q] = gv * fmaxf(acc[n0][q], 0.f) + (1.f - gv) * fhet[n0][q];
      }
    frag_store(Rb, ogv, p, sub, l15, lhi);
    fragT_store(Qb, ogv, p, sub, l15, lhi);
  }
  __syncthreads();                                       // B5

  // ---- M3: t = og @ wqk -> P ----
  ZACC(acc);
  mm_full(acc, Rb, Wb, p, sub, l15, lhi);
  frag_store(Pb, acc, p, sub, l15, lhi);
  __syncthreads();                                       // B6

  stageW(Wb, ws16 + 16384, tid);                         // wvT (overlaps M4/M5)

  // ---- M4: logits; no-max masked softmax ----
  ZACC(acc);
  mm_full(acc, Pb, Rb, p, sub, l15, lhi);
  float ee[4][4];
  {
    float msv[4];
    #pragma unroll
    for (int n0 = 0; n0 < 4; n0++) msv[n0] = msh[(sub*4 + n0)*16 + l15];
    #pragma unroll
    for (int q = 0; q < 4; q++){
      const int row = 16*p + 4*lhi + q;
      float se = 0.f;
      #pragma unroll
      for (int n0 = 0; n0 < 4; n0++){
        const float e = __expf(acc[n0][q]) * msv[n0];
        ee[n0][q] = e; se += e;
      }
      #pragma unroll
      for (int o = 1; o < 16; o <<= 1) se += __shfl_xor(se, o);
      if (l15 == 0) csum[row*2 + sub] = se;
    }
  }
  __syncthreads();                                       // B7
  #pragma unroll
  for (int q = 0; q < 4; q++){
    const int row = 16*p + 4*lhi + q;
    const float inv = frcp(csum[row*2] + csum[row*2 + 1]);
    #pragma unroll
    for (int n0 = 0; n0 < 4; n0++){
      const float a = ee[n0][q] * inv;
      const int col = (sub*4 + n0)*16 + l15;
      att_o[(size_t)row*128 + col] = a;                  // f32
      *(unsigned short*)(Pb + SW(row, 2*col)) = f2b(a);
    }
  }
  __syncthreads();                                       // B8

  uint4 w1r[2];
  loadW(w1r, ws16 + 32768, tid);                         // w1T -> regs (in flight)

  // ---- M5: u = attn @ og -> R ----
  ZACC(acc);
  mm_full(acc, Pb, Qb, p, sub, l15, lhi);
  frag_store(Rb, acc, p, sub, l15, lhi);
  __syncthreads();                                       // B9

  // ---- M6: sa = LN(u @ wv)*m -> Q + global + regs ----
  ZACC(acc);
  mm_full(acc, Rb, Wb, p, sub, l15, lhi);
  f32x4 sav[4];
  {
    #pragma unroll
    for (int q = 0; q < 4; q++){
      const int row = 16*p + 4*lhi + q;
      float s1 = 0.f, s2 = 0.f;
      #pragma unroll
      for (int n0 = 0; n0 < 4; n0++){ const float v = acc[n0][q]; s1 += v; s2 += v*v; }
      #pragma unroll
      for (int o = 1; o < 16; o <<= 1){ s1 += __shfl_xor(s1, o); s2 += __shfl_xor(s2, o); }
      if (l15 == 0){ csum[row*4 + sub*2] = s1; csum[row*4 + sub*2 + 1] = s2; }
    }
  }
  __syncthreads();                                       // B10
  {
    float gsa[4], bsa[4];
    #pragma unroll
    for (int n0 = 0; n0 < 4; n0++){ const int c = (sub*4+n0)*16 + l15; gsa[n0] = g_sa[c]; bsa[n0] = be_sa[c]; }
    #pragma unroll
    for (int q = 0; q < 4; q++){
      const int row = 16*p + 4*lhi + q;
      const float s1 = csum[row*4] + csum[row*4 + 2];
      const float s2 = csum[row*4 + 1] + csum[row*4 + 3];
      const float mean = s1 * 0.0078125f;
      const float var  = s2 * 0.0078125f - mean*mean;
      const float rstd = __frsqrt_rn(var + 1e-3f);
      const float mr = msh[row];
      #pragma unroll
      for (int n0 = 0; n0 < 4; n0++){
        const float y = ((acc[n0][q] - mean) * rstd * gsa[n0] + bsa[n0]) * mr;
        sav[n0][q] = y;
        sa_o[(size_t)row*128 + (sub*4+n0)*16 + l15] = y;  // f32
      }
    }
    frag_store(Qb, sav, p, sub, l15, lhi);
  }
  __syncthreads();                                       // B11
  writeW(Wb, w1r, tid);                                  // w1T -> LDS
  __syncthreads();                                       // B12

  // ---- M7: d1 = relu(sa @ w1 + b1) -> P ----
  ZACC(acc);
  mm_full(acc, Qb, Wb, p, sub, l15, lhi);
  {
    f32x4 d1v[4];
    #pragma unroll
    for (int n0 = 0; n0 < 4; n0++){
      const float b1v = b1[(sub*4 + n0)*16 + l15];
      #pragma unroll
      for (int q = 0; q < 4; q++) d1v[n0][q] = fmaxf(acc[n0][q] + b1v, 0.f);
    }
    frag_store(Pb, d1v, p, sub, l15, lhi);
  }
  uint4 w2r[2];
  loadW(w2r, ws16 + 49152, tid);                         // w2T -> regs
  __syncthreads();                                       // B13
  writeW(Wb, w2r, tid);
  __syncthreads();                                       // B14

  // ---- M8: d2=relu(d1@w2+b2); dense=LN(d2+sa)*m -> global; pool ----
  ZACC(acc);
  mm_full(acc, Pb, Wb, p, sub, l15, lhi);
  {
    float b2v[4], gov[4], bov[4], dd[4][4];
    #pragma unroll
    for (int n0 = 0; n0 < 4; n0++){
      const int c = (sub*4 + n0)*16 + l15;
      b2v[n0] = b2[c]; gov[n0] = g_out[c]; bov[n0] = be_out[c];
    }
    #pragma unroll
    for (int q = 0; q < 4; q++){
      const int row = 16*p + 4*lhi + q;
      float s1 = 0.f, s2 = 0.f;
      #pragma unroll
      for (int n0 = 0; n0 < 4; n0++){
        const float v = fmaxf(acc[n0][q] + b2v[n0], 0.f) + sav[n0][q];
        dd[n0][q] = v; s1 += v; s2 += v*v;
      }
      #pragma unroll
      for (int o = 1; o < 16; o <<= 1){ s1 += __shfl_xor(s1, o); s2 += __shfl_xor(s2, o); }
      if (l15 == 0){ csum[row*4 + sub*2] = s1; csum[row*4 + sub*2 + 1] = s2; }
    }
    __syncthreads();                                     // B15
    float cs[4] = {0.f, 0.f, 0.f, 0.f};
    #pragma unroll
    for (int q = 0; q < 4; q++){
      const int row = 16*p + 4*lhi + q;
      const float s1 = csum[row*4] + csum[row*4 + 2];
      const float s2 = csum[row*4 + 1] + csum[row*4 + 3];
      const float mean = s1 * 0.0078125f;
      const float var  = s2 * 0.0078125f - mean*mean;
      const float rstd = __frsqrt_rn(var + 1e-3f);
      const float mr = msh[row];
      #pragma unroll
      for (int n0 = 0; n0 < 4; n0++){
        const float y = ((dd[n0][q] - mean) * rstd * gov[n0] + bov[n0]) * mr;
        den_o[(size_t)row*128 + (sub*4+n0)*16 + l15] = y;  // f32
        cs[n0] += y;
      }
    }
    #pragma unroll
    for (int n0 = 0; n0 < 4; n0++){
      float v = cs[n0];
      v += __shfl_xor(v, 16); v += __shfl_xor(v, 32);
      if (lhi == 0) pool[p*128 + (sub*4 + n0)*16 + l15] = v;
    }
  }
  __syncthreads();                                       // B16
  if (tid < 128){
    float s = 0.f;
    #pragma unroll
    for (int q = 0; q < 8; q++) s += pool[q*128 + tid];
    const float n = *sN;
    out0[(size_t)g*128 + tid] = (n > 0.f) ? (s * frcp(n)) : 0.f;
  }
}

extern "C" void kernel_launch(void* const* d_in, const int* in_sizes, int n_in,
                              void* d_out, int out_size, void* d_ws, size_t ws_size,
                              hipStream_t stream) {
  (void)in_sizes; (void)n_in; (void)out_size; (void)ws_size;
  const float* x     = (const float*)d_in[0];
  const float* mask  = (const float*)d_in[1];
  const float* theta = (const float*)d_in[2];
  const float* w_t   = (const float*)d_in[3];
  const float* b_t   = (const float*)d_in[4];
  const float* wq    = (const float*)d_in[5];
  const float* wk    = (const float*)d_in[6];
  const float* wvp   = (const float*)d_in[7];
  const float* w1    = (const float*)d_in[8];
  const float* b1    = (const float*)d_in[9];
  const float* w2    = (const float*)d_in[10];
  const float* b2    = (const float*)d_in[11];
  const float* g_sa  = (const float*)d_in[12];
  const float* be_sa = (const float*)d_in[13];
  const float* g_out = (const float*)d_in[14];
  const float* be_out= (const float*)d_in[15];
  unsigned short* ws16 = (unsigned short*)d_ws;

  prep_wqkT<<<dim3(128), dim3(128), 0, stream>>>(wq, wk, ws16);
  prep_T<<<dim3(224), dim3(256), 0, stream>>>(wvp, w1, w2, theta, w_t, ws16);

  (void)hipFuncSetAttribute(reinterpret_cast<const void*>(fused_gcn),
                            hipFuncAttributeMaxDynamicSharedMemorySize, SMEM_SZ);
  fused_gcn<<<dim3(Gg), dim3(NT), SMEM_SZ, stream>>>(
      x, mask, b_t, ws16, b1, b2, g_sa, be_sa, g_out, be_out, (float*)d_out);
}